// Round 2
// baseline (7429.757 us; speedup 1.0000x reference)
//
#include <hip/hip_runtime.h>

#define B_ 256
#define T_ 128
#define F_ 784
#define FP_ 800          // F padded to multiple of 32
#define H_ 1024
#define NG_ 4096         // 4*H
#define C_ 10
#define TC_ 16           // time-chunk length
#define MC_ (B_ * TC_)   // rows per chunk = 4096
#define BN_EPS 1e-3f

typedef short s16x8 __attribute__((ext_vector_type(8)));
typedef float f32x4 __attribute__((ext_vector_type(4)));

__device__ __forceinline__ ushort f2bf(float f) {
    union { float f; unsigned u; } v; v.f = f;
    unsigned r = v.u + 0x7FFFu + ((v.u >> 16) & 1u);
    return (ushort)(r >> 16);
}
__device__ __forceinline__ float bf2f(ushort h) {
    union { unsigned u; float f; } v; v.u = ((unsigned)h) << 16;
    return v.f;
}
__device__ __forceinline__ float sigm(float x) {
    return 1.0f / (1.0f + __expf(-x));
}

// ---------------- prep: BN scale/shift, W_out^T bf16 (padded to 16 rows), zero state ----------
__global__ __launch_bounds__(256) void prep_params(
    const float* __restrict__ gamma1, const float* __restrict__ beta1,
    const float* __restrict__ mean1, const float* __restrict__ var1,
    const float* __restrict__ gamma2, const float* __restrict__ beta2,
    const float* __restrict__ mean2, const float* __restrict__ var2,
    const float* __restrict__ W_out,
    float* __restrict__ sc1, float* __restrict__ sh1,
    float* __restrict__ sc2, float* __restrict__ sh2,
    ushort* __restrict__ woutT, float* __restrict__ c_buf, ushort* __restrict__ h_buf)
{
    int idx = blockIdx.x * 256 + threadIdx.x;
    if (idx < B_ * H_) { c_buf[idx] = 0.0f; h_buf[idx] = 0; }  // h slot 0 = h_{-1} = 0
    if (idx < H_) {
        float s1 = gamma1[idx] * rsqrtf(var1[idx] + BN_EPS);
        sc1[idx] = s1; sh1[idx] = beta1[idx] - mean1[idx] * s1;
        float s2 = gamma2[idx] * rsqrtf(var2[idx] + BN_EPS);
        sc2[idx] = s2; sh2[idx] = beta2[idx] - mean2[idx] * s2;
    }
    if (idx < 16 * H_) {
        int n = idx >> 10, k = idx & (H_ - 1);
        woutT[idx] = (n < C_) ? f2bf(W_out[k * C_ + n]) : (ushort)0;
    }
}

// ---------------- generic f32 (K,N) -> bf16 (N,Kpad) transpose, zero-padded ----------------
__global__ __launch_bounds__(256) void transpose_f32_to_bf16(
    const float* __restrict__ src, ushort* __restrict__ dst, int K, int N, int Kpad)
{
    __shared__ float tile[32][33];
    int tx = threadIdx.x & 31, ty = threadIdx.x >> 5;
    int bx = blockIdx.x, by = blockIdx.y;
    int col = bx * 32 + tx;
    for (int l = 0; l < 4; ++l) {
        int row = by * 32 + ty + l * 8;
        tile[ty + l * 8][tx] = (row < K && col < N) ? src[(long)row * N + col] : 0.0f;
    }
    __syncthreads();
    for (int l = 0; l < 4; ++l) {
        int n = bx * 32 + ty + l * 8;
        int k = by * 32 + tx;
        if (n < N && k < Kpad) dst[(long)n * Kpad + k] = f2bf(tile[tx][ty + l * 8]);
    }
}

// ---------------- GEMM1 (per chunk): feat_c = tanh(BN(tanh(x_chunk @ W_fe + b))) ------------
// chunk rows m = t_local*B + b ; x row = (b, t0+t_local)
__global__ __launch_bounds__(256) void gemm1_c(
    const float* __restrict__ x, const ushort* __restrict__ wfeT,
    const float* __restrict__ b_fe, const float* __restrict__ sc1, const float* __restrict__ sh1,
    ushort* __restrict__ feat_c, int t0)
{
    __shared__ __align__(16) ushort As[128 * 40];
    __shared__ __align__(16) ushort Bs[128 * 40];
    int tid = threadIdx.x;
    int m0 = blockIdx.y * 128, n0 = blockIdx.x * 128;
    int wave = tid >> 6, lane = tid & 63;
    int wm = wave >> 1, wn = wave & 1;
    int l15 = lane & 15, quad = lane >> 4;

    f32x4 zero = {0.f, 0.f, 0.f, 0.f};
    f32x4 acc[4][4];
    for (int i = 0; i < 4; i++) for (int j = 0; j < 4; j++) acc[i][j] = zero;

    for (int kk = 0; kk < FP_ / 32; ++kk) {
        int kb = kk * 32;
        for (int c = tid; c < 1024; c += 256) {
            int row = c >> 3, ch = c & 7;
            int m = m0 + row;
            int b = m & (B_ - 1), tl = m >> 8;
            int k = kb + ch * 4;
            float4 v = make_float4(0.f, 0.f, 0.f, 0.f);
            if (k < F_) v = *(const float4*)(x + ((long)b * T_ + t0 + tl) * F_ + k);
            ushort4 bb; bb.x = f2bf(v.x); bb.y = f2bf(v.y); bb.z = f2bf(v.z); bb.w = f2bf(v.w);
            *(ushort4*)&As[row * 40 + ch * 4] = bb;
        }
        for (int c = tid; c < 512; c += 256) {
            int row = c >> 2, ch = c & 3;
            *(uint4*)&Bs[row * 40 + ch * 8] =
                *(const uint4*)(wfeT + (long)(n0 + row) * FP_ + kb + ch * 8);
        }
        __syncthreads();
        s16x8 af[4], bfr[4];
        for (int i = 0; i < 4; i++) af[i]  = *(const s16x8*)&As[(wm * 64 + i * 16 + l15) * 40 + quad * 8];
        for (int j = 0; j < 4; j++) bfr[j] = *(const s16x8*)&Bs[(wn * 64 + j * 16 + l15) * 40 + quad * 8];
        for (int i = 0; i < 4; i++)
            for (int j = 0; j < 4; j++)
                acc[i][j] = __builtin_amdgcn_mfma_f32_16x16x32_bf16(af[i], bfr[j], acc[i][j], 0, 0, 0);
        __syncthreads();
    }
    for (int j = 0; j < 4; j++) {
        int n_g = n0 + wn * 64 + j * 16 + l15;
        float bia = b_fe[n_g], s = sc1[n_g], sh = sh1[n_g];
        for (int i = 0; i < 4; i++) {
            int mb = m0 + wm * 64 + i * 16 + quad * 4;
            for (int r = 0; r < 4; r++) {
                float v = tanhf(acc[i][j][r] + bia);
                v = tanhf(v * s + sh);
                feat_c[(long)(mb + r) * H_ + n_g] = f2bf(v);
            }
        }
    }
}

// ---------------- GEMM2 (per chunk): zx_c = feat_c @ kernel -> bf16 (MC_, 4H) --------------
__global__ __launch_bounds__(256) void gemm2_c(
    const ushort* __restrict__ feat_c, const ushort* __restrict__ kT,
    ushort* __restrict__ zx_c)
{
    __shared__ __align__(16) ushort As[128 * 40];
    __shared__ __align__(16) ushort Bs[128 * 40];
    int tid = threadIdx.x;
    int m0 = blockIdx.y * 128, n0 = blockIdx.x * 128;
    int wave = tid >> 6, lane = tid & 63;
    int wm = wave >> 1, wn = wave & 1;
    int l15 = lane & 15, quad = lane >> 4;

    f32x4 zero = {0.f, 0.f, 0.f, 0.f};
    f32x4 acc[4][4];
    for (int i = 0; i < 4; i++) for (int j = 0; j < 4; j++) acc[i][j] = zero;

    for (int kk = 0; kk < H_ / 32; ++kk) {
        int kb = kk * 32;
        for (int c = tid; c < 1024; c += 256) {
            if (c < 512) {
                int row = c >> 2, ch = c & 3;
                *(uint4*)&As[row * 40 + ch * 8] =
                    *(const uint4*)(feat_c + (long)(m0 + row) * H_ + kb + ch * 8);
            } else {
                int cb = c - 512;
                int row = cb >> 2, ch = cb & 3;
                *(uint4*)&Bs[row * 40 + ch * 8] =
                    *(const uint4*)(kT + (long)(n0 + row) * H_ + kb + ch * 8);
            }
        }
        __syncthreads();
        s16x8 af[4], bfr[4];
        for (int i = 0; i < 4; i++) af[i]  = *(const s16x8*)&As[(wm * 64 + i * 16 + l15) * 40 + quad * 8];
        for (int j = 0; j < 4; j++) bfr[j] = *(const s16x8*)&Bs[(wn * 64 + j * 16 + l15) * 40 + quad * 8];
        for (int i = 0; i < 4; i++)
            for (int j = 0; j < 4; j++)
                acc[i][j] = __builtin_amdgcn_mfma_f32_16x16x32_bf16(af[i], bfr[j], acc[i][j], 0, 0, 0);
        __syncthreads();
    }
    for (int j = 0; j < 4; j++) {
        int n_g = n0 + wn * 64 + j * 16 + l15;
        for (int i = 0; i < 4; i++) {
            int mb = m0 + wm * 64 + i * 16 + quad * 4;
            for (int r = 0; r < 4; r++)
                zx_c[(long)(mb + r) * NG_ + n_g] = f2bf(acc[i][j][r]);
        }
    }
}

// ---------------- one LSTM time step: z = h_{t-1} @ R (+ zx_t + bias) -> cell -> h_t -------
// grid 256 blocks: 8 m-tiles (32 batch rows) x 32 u-tiles (32 hidden units, 4 gate strips)
__global__ __launch_bounds__(256) void lstm_step(
    const ushort* __restrict__ h_in, ushort* __restrict__ h_out,
    float* __restrict__ c_buf, const ushort* __restrict__ rT,
    const ushort* __restrict__ zx_t,
    const float* __restrict__ bias, const float* __restrict__ pi,
    const float* __restrict__ pf, const float* __restrict__ po)
{
    __shared__ __align__(16) ushort As[32 * 40];
    __shared__ __align__(16) ushort Bs[4 * 32 * 40];
    int tid = threadIdx.x;
    int mt = blockIdx.x & 7, ut = blockIdx.x >> 3;
    int wave = tid >> 6, lane = tid & 63;
    int wm = wave >> 1, wu = wave & 1;
    int l15 = lane & 15, quad = lane >> 4;

    f32x4 zero = {0.f, 0.f, 0.f, 0.f};
    f32x4 acc[4];
    for (int g = 0; g < 4; g++) acc[g] = zero;

    for (int kk = 0; kk < H_ / 32; ++kk) {
        int kb = kk * 32;
        for (int c = tid; c < 640; c += 256) {
            if (c < 128) {
                int row = c >> 2, ch = c & 3;
                *(uint4*)&As[row * 40 + ch * 8] =
                    *(const uint4*)(h_in + (long)(mt * 32 + row) * H_ + kb + ch * 8);
            } else {
                int cb = c - 128;
                int g = cb >> 7, row = (cb >> 2) & 31, ch = cb & 3;
                *(uint4*)&Bs[(g * 32 + row) * 40 + ch * 8] =
                    *(const uint4*)(rT + (long)(g * H_ + ut * 32 + row) * H_ + kb + ch * 8);
            }
        }
        __syncthreads();
        s16x8 af = *(const s16x8*)&As[(wm * 16 + l15) * 40 + quad * 8];
        for (int g = 0; g < 4; g++) {
            s16x8 bfr = *(const s16x8*)&Bs[(g * 32 + wu * 16 + l15) * 40 + quad * 8];
            acc[g] = __builtin_amdgcn_mfma_f32_16x16x32_bf16(af, bfr, acc[g], 0, 0, 0);
        }
        __syncthreads();
    }

    int u_g = ut * 32 + wu * 16 + l15;
    float bi = bias[u_g], bf_ = bias[H_ + u_g], bc = bias[2 * H_ + u_g], bo = bias[3 * H_ + u_g];
    float pI = pi[u_g], pF = pf[u_g], pO = po[u_g];
    for (int r = 0; r < 4; ++r) {
        int b_g = mt * 32 + wm * 16 + quad * 4 + r;
        const ushort* zr = zx_t + (long)b_g * NG_;
        float zi = acc[0][r] + bi  + bf2f(zr[u_g]);
        float zf = acc[1][r] + bf_ + bf2f(zr[H_ + u_g]);
        float zc = acc[2][r] + bc  + bf2f(zr[2 * H_ + u_g]);
        float zo = acc[3][r] + bo  + bf2f(zr[3 * H_ + u_g]);
        float c_old = c_buf[b_g * H_ + u_g];
        float ig = sigm(zi + c_old * pI);
        float fg = sigm(zf + c_old * pF);
        float cn = fg * c_old + ig * tanhf(zc);
        float og = sigm(zo + cn * pO);
        float h = og * tanhf(cn);
        c_buf[b_g * H_ + u_g] = cn;
        h_out[(long)b_g * H_ + u_g] = f2bf(h);
    }
}

// ---------------- final (per chunk): out = tanh(BN(h)) @ W_out  (N padded 10->16) ----------
// rows = h_buf slots 1..TC, ordered (t_local*B + b)
__global__ __launch_bounds__(256) void final_chunk(
    const ushort* __restrict__ h_buf, const ushort* __restrict__ woutT,
    const float* __restrict__ sc2, const float* __restrict__ sh2,
    float* __restrict__ out, int t0)
{
    __shared__ __align__(16) ushort As[128 * 40];
    __shared__ __align__(16) ushort Bs[16 * 40];
    int tid = threadIdx.x;
    long r0 = (long)blockIdx.x * 128;
    const ushort* hbase = h_buf + (long)B_ * H_ + r0 * H_;   // slot 1 onward
    int wave = tid >> 6, lane = tid & 63;
    int l15 = lane & 15, quad = lane >> 4;

    f32x4 zero = {0.f, 0.f, 0.f, 0.f};
    f32x4 acc[2]; acc[0] = zero; acc[1] = zero;

    for (int kk = 0; kk < H_ / 32; ++kk) {
        int kb = kk * 32;
        for (int c = tid; c < 512; c += 256) {
            int row = c >> 2, ch = c & 3;
            int k = kb + ch * 8;
            union { uint4 u4; ushort s[8]; } in, ov;
            in.u4 = *(const uint4*)(hbase + (long)row * H_ + k);
            float4 sa = *(const float4*)(sc2 + k), sb = *(const float4*)(sc2 + k + 4);
            float4 ba = *(const float4*)(sh2 + k), bb = *(const float4*)(sh2 + k + 4);
            ov.s[0] = f2bf(tanhf(bf2f(in.s[0]) * sa.x + ba.x));
            ov.s[1] = f2bf(tanhf(bf2f(in.s[1]) * sa.y + ba.y));
            ov.s[2] = f2bf(tanhf(bf2f(in.s[2]) * sa.z + ba.z));
            ov.s[3] = f2bf(tanhf(bf2f(in.s[3]) * sa.w + ba.w));
            ov.s[4] = f2bf(tanhf(bf2f(in.s[4]) * sb.x + bb.x));
            ov.s[5] = f2bf(tanhf(bf2f(in.s[5]) * sb.y + bb.y));
            ov.s[6] = f2bf(tanhf(bf2f(in.s[6]) * sb.z + bb.z));
            ov.s[7] = f2bf(tanhf(bf2f(in.s[7]) * sb.w + bb.w));
            *(uint4*)&As[row * 40 + ch * 8] = ov.u4;
        }
        if (tid < 64) {
            int row = tid >> 2, ch = tid & 3;
            *(uint4*)&Bs[row * 40 + ch * 8] = *(const uint4*)(woutT + row * H_ + kb + ch * 8);
        }
        __syncthreads();
        s16x8 bfr = *(const s16x8*)&Bs[l15 * 40 + quad * 8];
        for (int i = 0; i < 2; i++) {
            s16x8 af = *(const s16x8*)&As[(wave * 32 + i * 16 + l15) * 40 + quad * 8];
            acc[i] = __builtin_amdgcn_mfma_f32_16x16x32_bf16(af, bfr, acc[i], 0, 0, 0);
        }
        __syncthreads();
    }
    if (l15 < C_) {
        for (int i = 0; i < 2; i++)
            for (int r = 0; r < 4; r++) {
                long rg = r0 + wave * 32 + i * 16 + quad * 4 + r;  // = tl*B + b
                int tl = (int)(rg >> 8);
                int b  = (int)(rg & (B_ - 1));
                out[((long)b * T_ + t0 + tl) * C_ + l15] = acc[i][r];
            }
    }
}

extern "C" void kernel_launch(void* const* d_in, const int* in_sizes, int n_in,
                              void* d_out, int out_size, void* d_ws, size_t ws_size,
                              hipStream_t stream)
{
    const float* x       = (const float*)d_in[0];
    const float* W_fe    = (const float*)d_in[1];
    const float* b_fe    = (const float*)d_in[2];
    const float* gamma1  = (const float*)d_in[3];
    const float* beta1   = (const float*)d_in[4];
    const float* mean1   = (const float*)d_in[5];
    const float* var1    = (const float*)d_in[6];
    const float* kernelw = (const float*)d_in[7];
    const float* reck    = (const float*)d_in[8];
    const float* bias    = (const float*)d_in[9];
    const float* peep_i  = (const float*)d_in[10];
    const float* peep_f  = (const float*)d_in[11];
    const float* peep_o  = (const float*)d_in[12];
    const float* gamma2  = (const float*)d_in[13];
    const float* beta2   = (const float*)d_in[14];
    const float* mean2   = (const float*)d_in[15];
    const float* var2    = (const float*)d_in[16];
    const float* W_out   = (const float*)d_in[17];
    float* out = (float*)d_out;

    char* ws = (char*)d_ws;
    size_t o = 0;
    ushort* wfeT  = (ushort*)(ws + o); o += (size_t)H_ * FP_ * 2;              // 1.64 MB
    ushort* kT    = (ushort*)(ws + o); o += (size_t)NG_ * H_ * 2;              // 8.39 MB
    ushort* rT    = (ushort*)(ws + o); o += (size_t)NG_ * H_ * 2;              // 8.39 MB
    ushort* feat_c= (ushort*)(ws + o); o += (size_t)MC_ * H_ * 2;              // 8.39 MB
    ushort* zx_c  = (ushort*)(ws + o); o += (size_t)MC_ * NG_ * 2;             // 33.55 MB
    ushort* h_buf = (ushort*)(ws + o); o += (size_t)(TC_ + 1) * B_ * H_ * 2;   // 8.91 MB
    float*  c_buf = (float*)(ws + o);  o += (size_t)B_ * H_ * 4;               // 1.05 MB
    float*  sc1   = (float*)(ws + o);  o += 4096;
    float*  sh1   = (float*)(ws + o);  o += 4096;
    float*  sc2   = (float*)(ws + o);  o += 4096;
    float*  sh2   = (float*)(ws + o);  o += 4096;
    ushort* woutT = (ushort*)(ws + o); o += 16 * H_ * 2;
    // total ~70.4 MB

    prep_params<<<dim3(B_ * H_ / 256), dim3(256), 0, stream>>>(
        gamma1, beta1, mean1, var1, gamma2, beta2, mean2, var2, W_out,
        sc1, sh1, sc2, sh2, woutT, c_buf, h_buf);

    transpose_f32_to_bf16<<<dim3(32, 25), dim3(256), 0, stream>>>(W_fe, wfeT, F_, H_, FP_);
    transpose_f32_to_bf16<<<dim3(128, 32), dim3(256), 0, stream>>>(kernelw, kT, H_, NG_, H_);
    transpose_f32_to_bf16<<<dim3(128, 32), dim3(256), 0, stream>>>(reck, rT, H_, NG_, H_);

    const long BH = (long)B_ * H_;
    for (int ci = 0; ci < T_ / TC_; ++ci) {
        int t0 = ci * TC_;
        gemm1_c<<<dim3(H_ / 128, MC_ / 128), dim3(256), 0, stream>>>(
            x, wfeT, b_fe, sc1, sh1, feat_c, t0);
        gemm2_c<<<dim3(NG_ / 128, MC_ / 128), dim3(256), 0, stream>>>(feat_c, kT, zx_c);
        for (int tl = 0; tl < TC_; ++tl) {
            const ushort* h_in = h_buf + (size_t)((tl == 0) ? (ci == 0 ? 0 : TC_) : tl) * BH;
            ushort* h_out = h_buf + (size_t)(tl + 1) * BH;
            lstm_step<<<dim3(256), dim3(256), 0, stream>>>(
                h_in, h_out, c_buf, rT, zx_c + (long)tl * B_ * NG_,
                bias, peep_i, peep_f, peep_o);
        }
        final_chunk<<<dim3(MC_ / 128), dim3(256), 0, stream>>>(
            h_buf, woutT, sc2, sh2, out, t0);
    }
}